// Round 6
// baseline (11.656 us; speedup 1.0000x reference)
//
#include <hip/hip_runtime.h>

// QNN_Q3: 3-qubit StronglyEntanglingLayers, B=128, T=64, D=96, 3 chained
// layers, nb=32, vqc_depth=2. 2 circuits (b, b+8) per thread, SoA v2f packed
// complex math; rot table (t-shared) built per block in LDS.
// Round 5: (a) XCD-aware block remap — the 8 blocks sharing a t are stride-64
// apart -> same XCD L2, theta fetched once per XCD after the harness's
// L2/L3-evicting poison fill; (b) coalesced float4 theta->LDS staging
// (replaces scattered scalar cold-miss reads); (c) layer loop not unrolled
// (icache footprint ~1/3; 256 CUs re-fetch code every replay).

#define T_DIM 64
#define D_DIM 96
#define NB 32
#define NLAYER 3
#define ROTS_PER_T (NLAYER * 6 * NB)            // 576
#define THETA_PER_T (NLAYER * NB * 18)          // 1728 floats
#define THETA_F4 (THETA_PER_T / 4)              // 432

typedef float v2f __attribute__((ext_vector_type(2)));

struct c2 { v2f re, im; };   // one amplitude, two packed circuits

__device__ __forceinline__ c2 cmul2(c2 a, c2 b) {
    c2 r;
    r.re = a.re * b.re - a.im * b.im;
    r.im = a.re * b.im + a.im * b.re;
    return r;
}

// Rot 2x2 on a REAL 1-qubit state (c,s): U00=X+iY U01=-U-iV U10=U-iV U11=X-iY
__device__ __forceinline__ void apply1q(float4 r, v2f c, v2f s, c2& e0, c2& e1) {
    e0.re = r.x * c - r.z * s;          // X c - U s
    e0.im = r.y * c - r.w * s;          // Y c - V s
    e1.re = r.z * c + r.x * s;          // U c + X s
    e1.im = -(r.w * c + r.y * s);       // -(V c + Y s)
}

// Full complex butterfly on packed psi
__device__ __forceinline__ void gate_pk(c2 psi[8], float4 r, int bit) {
    const v2f X = {r.x, r.x}, Y = {r.y, r.y}, U = {r.z, r.z}, V = {r.w, r.w};
#pragma unroll
    for (int k = 0; k < 8; ++k) {
        if (k & bit) continue;
        c2 p0 = psi[k], p1 = psi[k | bit], o0, o1;
        o0.re = X * p0.re - Y * p0.im - U * p1.re + V * p1.im;
        o0.im = Y * p0.re + X * p0.im - V * p1.re - U * p1.im;
        o1.re = U * p0.re + V * p0.im + X * p1.re + Y * p1.im;
        o1.im = U * p0.im - V * p0.re + X * p1.im - Y * p1.re;
        psi[k] = o0; psi[k | bit] = o1;
    }
}

__device__ __forceinline__ void cnot_c2(c2 psi[8], int cb, int tb) {
#pragma unroll
    for (int k = 0; k < 8; ++k) {
        if ((k & cb) && !(k & tb)) {
            c2 tmp = psi[k]; psi[k] = psi[k | tb]; psi[k | tb] = tmp;
        }
    }
}

__device__ __forceinline__ void sc2(v2f a, v2f& s, v2f& c) {
    float sx, cx, sy, cy;
    __sincosf(0.5f * a.x, &sx, &cx);
    __sincosf(0.5f * a.y, &sy, &cy);
    s = (v2f){sx, sy}; c = (v2f){cx, cy};
}

__global__ __launch_bounds__(256, 2) void qnn_fused(const float* __restrict__ x,
                                                    const float* __restrict__ theta,
                                                    float* __restrict__ out) {
    __shared__ float  thetaS[THETA_PER_T];   // 6912 B
    __shared__ float4 rotS[ROTS_PER_T];      // 9216 B

    const int tid = threadIdx.x;
    const int t  = blockIdx.x & 63;          // same-t blocks are 64 apart -> same XCD
    const int bg = blockIdx.x >> 6;          // 8 groups of 16 b
    const int pr = tid >> 5;                 // 0..7
    const int i  = tid & 31;                 // circuit index within (b,t)
    const int b0 = bg * 16 + pr;
    const int bt0 = b0 * T_DIM + t;
    const int bt1 = bt0 + 8 * T_DIM;         // b1 = b0 + 8

    // ---- early x loads (latency hides under staging + rot build) ----
    const float* xp0 = x + (size_t)bt0 * D_DIM + 3 * i;
    const float* xp1 = x + (size_t)bt1 * D_DIM + 3 * i;
    v2f ang0 = {xp0[0], xp1[0]};
    v2f ang1 = {xp0[1], xp1[1]};
    v2f ang2 = {xp0[2], xp1[2]};

    // ---- coalesced theta[t] staging (float4) ----
    const float4* gth4 = (const float4*)(theta + (size_t)t * THETA_PER_T);
    float4* ts4 = (float4*)thetaS;
    ts4[tid] = gth4[tid];
    if (tid < THETA_F4 - 256) ts4[tid + 256] = gth4[tid + 256];
    __syncthreads();

    // ---- rot table for this t: 576 entries ----
#pragma unroll
    for (int r5 = 0; r5 < 3; ++r5) {
        int idx = tid + r5 * 256;
        if (idx < ROTS_PER_T) {
            int l   = (idx >= 384) ? 2 : (idx >= 192 ? 1 : 0);
            int rem = idx - l * 192;
            int j   = rem >> 5;              // vl*3+q
            int ii  = rem & 31;              // circuit block
            const float* p = &thetaS[((l * NB + ii) * 6 + j) * 3];
            float phi = p[0], tht = p[1], omg = p[2];
            float st, ct; __sincosf(0.5f * tht, &st, &ct);
            float sa, ca; __sincosf(-0.5f * (phi + omg), &sa, &ca);  // a = ca+i*sa
            float sb, cb; __sincosf(0.5f * (phi - omg), &sb, &cb);   // b = cb+i*sb
            rotS[idx] = make_float4(ca * ct, sa * ct, cb * st, sb * st);
        }
    }
    __syncthreads();

    v2f res0 = {0.f, 0.f}, res1 = {0.f, 0.f}, res2 = {0.f, 0.f};
#pragma unroll 1
    for (int l = 0; l < NLAYER; ++l) {
        if (l) {
            // rewiring [3i-1, 3i+1, 3i+3] mod 96 within the 32-thread group
            int lm = (i + 31) & 31, lp = (i + 1) & 31;
            ang0 = (v2f){__shfl(res2.x, lm, 32), __shfl(res2.y, lm, 32)};
            ang1 = res1;
            ang2 = (v2f){__shfl(res0.x, lp, 32), __shfl(res0.y, lp, 32)};
        }
        float4 rr[6];
        const int base = l * 192 + i;
#pragma unroll
        for (int j = 0; j < 6; ++j) rr[j] = rotS[base + j * 32];

        v2f c0, s0, c1, s1, c2v, s2v;
        sc2(ang0, s0, c0); sc2(ang1, s1, c1); sc2(ang2, s2v, c2v);

        // vl=0: Rot on each 1-qubit factor (real input), then tensor expand
        c2 A0, A1, B0, B1, C0, C1;
        apply1q(rr[0], c0, s0, A0, A1);
        apply1q(rr[1], c1, s1, B0, B1);
        apply1q(rr[2], c2v, s2v, C0, C1);
        c2 T00 = cmul2(A0, B0), T01 = cmul2(A0, B1);
        c2 T10 = cmul2(A1, B0), T11 = cmul2(A1, B1);
        c2 psi[8];
        psi[0] = cmul2(T00, C0); psi[1] = cmul2(T00, C1);
        psi[2] = cmul2(T01, C0); psi[3] = cmul2(T01, C1);
        psi[4] = cmul2(T10, C0); psi[5] = cmul2(T10, C1);
        psi[6] = cmul2(T11, C0); psi[7] = cmul2(T11, C1);

        // vl=0 CNOT ring, range 1: (0->1),(1->2),(2->0); wire bit: 4>>q
        cnot_c2(psi, 4, 2); cnot_c2(psi, 2, 1); cnot_c2(psi, 1, 4);

        // vl=1: full complex Rots
        gate_pk(psi, rr[3], 4); gate_pk(psi, rr[4], 2); gate_pk(psi, rr[5], 1);

        // vl=1 CNOT ring, range 2: (0->2),(1->0),(2->1)
        cnot_c2(psi, 4, 1); cnot_c2(psi, 2, 4); cnot_c2(psi, 1, 2);

        // measurement: Z on each wire
        v2f pb[8];
#pragma unroll
        for (int k = 0; k < 8; ++k)
            pb[k] = psi[k].re * psi[k].re + psi[k].im * psi[k].im;
        v2f s01 = pb[0] + pb[1], s23 = pb[2] + pb[3];
        v2f s45 = pb[4] + pb[5], s67 = pb[6] + pb[7];
        v2f q0 = pb[0] + pb[4], q1 = pb[1] + pb[5];
        v2f q2 = pb[2] + pb[6], q3 = pb[3] + pb[7];
        res0 = (s01 + s23) - (s45 + s67);
        res1 = (q0 + q1) - (q2 + q3);
        res2 = (q0 + q2) - (q1 + q3);
    }

    float* op0 = out + (size_t)bt0 * D_DIM + 3 * i;
    float* op1 = out + (size_t)bt1 * D_DIM + 3 * i;
    op0[0] = res0.x; op0[1] = res1.x; op0[2] = res2.x;
    op1[0] = res0.y; op1[1] = res1.y; op1[2] = res2.y;
}

extern "C" void kernel_launch(void* const* d_in, const int* in_sizes, int n_in,
                              void* d_out, int out_size, void* d_ws, size_t ws_size,
                              hipStream_t stream) {
    const float* x = (const float*)d_in[0];       // (128, 64, 96) f32
    const float* theta = (const float*)d_in[1];   // (64, 3, 32, 2, 3, 3) f32
    float* out = (float*)d_out;                   // (128, 64, 96) f32

    // grid: 8 b-groups x 64 t (t = blk & 63 so t-sharing blocks co-locate per XCD)
    qnn_fused<<<64 * 8, 256, 0, stream>>>(x, theta, out);
}